// Round 1
// baseline (406.910 us; speedup 1.0000x reference)
//
#include <hip/hip_runtime.h>

// Projection of spherical range image -> point cloud.
// image: (2048, 8192, 4) f32, depth = channel 3.
// out:   (2048*8192, 3) f32  [x, y, z]
//
// yaw   = j/w * 2pi - pi            -> yaw_rev   = j/w - 0.5         (revolutions)
// pitch = (1 - i/h)*(30deg) - 15deg -> pitch_rev = (1-i/h)*(30/360) - 15/360
// x = d*cos(yaw); y = -d*sin(yaw); z = d*sin(pitch)
//
// v_sin_f32 / v_cos_f32 compute sin(2*pi*x) -- feed revolutions directly.

#define H 2048
#define W 8192

__global__ __launch_bounds__(256) void proj_kernel(const float4* __restrict__ img,
                                                   float4* __restrict__ out) {
    // each thread handles 4 consecutive pixels of one row
    int tid  = blockIdx.x * 256 + threadIdx.x;          // 0 .. H*W/4-1
    int base = tid * 4;                                 // first pixel index
    int i = base >> 13;                                 // / W (W = 8192)
    int j = base & (W - 1);

    const float inv_w  = 1.0f / (float)W;
    const float inv_h  = 1.0f / (float)H;
    const float span_r = 30.0f / 360.0f;                // fov span in revolutions
    const float down_r = 15.0f / 360.0f;

    float pitch_rev = (1.0f - (float)i * inv_h) * span_r - down_r;
    float sp = __builtin_amdgcn_sinf(pitch_rev);        // sin(pitch), shared across the 4 pixels

    // 4 coalesced 16B loads (lane stride 64B; 4 insts cover lines fully)
    float4 px0 = img[base + 0];
    float4 px1 = img[base + 1];
    float4 px2 = img[base + 2];
    float4 px3 = img[base + 3];

    float xyz[12];
    float d, yr, s, c;

    d = px0.w; yr = (float)(j + 0) * inv_w - 0.5f;
    s = __builtin_amdgcn_sinf(yr); c = __builtin_amdgcn_cosf(yr);
    xyz[0] = d * c; xyz[1] = -d * s; xyz[2] = d * sp;

    d = px1.w; yr = (float)(j + 1) * inv_w - 0.5f;
    s = __builtin_amdgcn_sinf(yr); c = __builtin_amdgcn_cosf(yr);
    xyz[3] = d * c; xyz[4] = -d * s; xyz[5] = d * sp;

    d = px2.w; yr = (float)(j + 2) * inv_w - 0.5f;
    s = __builtin_amdgcn_sinf(yr); c = __builtin_amdgcn_cosf(yr);
    xyz[6] = d * c; xyz[7] = -d * s; xyz[8] = d * sp;

    d = px3.w; yr = (float)(j + 3) * inv_w - 0.5f;
    s = __builtin_amdgcn_sinf(yr); c = __builtin_amdgcn_cosf(yr);
    xyz[9] = d * c; xyz[10] = -d * s; xyz[11] = d * sp;

    // 12 output floats per thread -> 3 fully-vectorized float4 stores
    float4* o = out + (size_t)tid * 3;
    o[0] = make_float4(xyz[0], xyz[1], xyz[2],  xyz[3]);
    o[1] = make_float4(xyz[4], xyz[5], xyz[6],  xyz[7]);
    o[2] = make_float4(xyz[8], xyz[9], xyz[10], xyz[11]);
}

extern "C" void kernel_launch(void* const* d_in, const int* in_sizes, int n_in,
                              void* d_out, int out_size, void* d_ws, size_t ws_size,
                              hipStream_t stream) {
    const float4* img = (const float4*)d_in[0];
    float4* out = (float4*)d_out;

    const int nthreads = H * W / 4;                    // 4,194,304
    dim3 block(256);
    dim3 grid(nthreads / 256);                         // 16,384 blocks
    proj_kernel<<<grid, block, 0, stream>>>(img, out);
}

// Round 2
// 406.466 us; speedup vs baseline: 1.0011x; 1.0011x over previous
//
#include <hip/hip_runtime.h>

// Spherical range image (2048,8192,4) f32 -> point cloud (2048*8192,3) f32.
// depth = channel 3. yaw_rev = j/W - 0.5 ; pitch_rev = (1-i/H)*(30/360) - 15/360.
// x = d*cos(yaw); y = -d*sin(yaw); z = d*sin(pitch).
// v_sin_f32 / v_cos_f32 take revolutions (sin(2*pi*x)) -- feed directly.
//
// Coalescing strategy: block of 256 threads owns 1024 CONSECUTIVE pixels.
//  - 4 loads/thread at p = k*256+tid -> 16B lane stride, perfectly coalesced.
//  - xyz staged in LDS (12 KiB), stride-3-dword writes (coprime with 32 banks,
//    conflict-free; <=2 lanes/bank is free on gfx950).
//  - read back as float4 -> 3 perfectly coalesced dwordx4 stores/thread.
// 1024 | W, so each block lies in a single row: pitch is block-uniform (scalar).

#define H 2048
#define W 8192
#define PIX_PER_BLOCK 1024

__global__ __launch_bounds__(256) void proj_kernel(const float4* __restrict__ img,
                                                   float4* __restrict__ out) {
    __shared__ __align__(16) float lds[PIX_PER_BLOCK * 3];   // 12 KiB

    const int tid = threadIdx.x;
    const int gbase = blockIdx.x * PIX_PER_BLOCK;            // first pixel of block
    const int i = blockIdx.x >> 3;                           // row (8 blocks per row)
    const int jbase = (blockIdx.x & 7) * PIX_PER_BLOCK;      // first column of block

    const float inv_w  = 1.0f / (float)W;
    const float inv_h  = 1.0f / (float)H;
    const float span_r = 30.0f / 360.0f;                     // fov span (revolutions)
    const float down_r = 15.0f / 360.0f;

    const float pitch_rev = (1.0f - (float)i * inv_h) * span_r - down_r;
    const float sp = __builtin_amdgcn_sinf(pitch_rev);       // block-uniform

    // Phase 1: coalesced loads + compute + stage to LDS (pixel-ordered floats)
#pragma unroll
    for (int k = 0; k < 4; ++k) {
        const int p = k * 256 + tid;                         // pixel within block
        const float4 px = img[gbase + p];
        const float d = px.w;
        const float yr = (float)(jbase + p) * inv_w - 0.5f;
        const float s = __builtin_amdgcn_sinf(yr);
        const float c = __builtin_amdgcn_cosf(yr);
        lds[p * 3 + 0] = d * c;                              // x
        lds[p * 3 + 1] = -d * s;                             // y
        lds[p * 3 + 2] = d * sp;                             // z
    }

    __syncthreads();

    // Phase 2: coalesced float4 stores (1024 px * 12 B = 768 float4 per block)
    const float4* lds4 = (const float4*)lds;
    float4* o = out + (size_t)blockIdx.x * 768;
#pragma unroll
    for (int s = 0; s < 3; ++s) {
        const int idx = s * 256 + tid;
        o[idx] = lds4[idx];
    }
}

extern "C" void kernel_launch(void* const* d_in, const int* in_sizes, int n_in,
                              void* d_out, int out_size, void* d_ws, size_t ws_size,
                              hipStream_t stream) {
    const float4* img = (const float4*)d_in[0];
    float4* out = (float4*)d_out;

    dim3 block(256);
    dim3 grid(H * W / PIX_PER_BLOCK);                        // 16,384 blocks
    proj_kernel<<<grid, block, 0, stream>>>(img, out);
}